// Round 10
// baseline (346.771 us; speedup 1.0000x reference)
//
#include <hip/hip_runtime.h>
#include <hip/hip_fp16.h>
#include <math.h>

// GCN encoder, N=100000, E=1600000, C_IN=32, C_H=C_OUT=64, G=64.
// CSR build via two-level LDS counting sort (NO global atomics).
// em weight = ew*dis[dst]; dis[src] folded into features.
// R12: TRANSFORM-FIRST (agg(h)W == agg(hW)): tiny GEMMs + lean agg.
// R13: contiguous 8-node chunks per wave + windowed edge-meta staging.
// R14: 4ch/lane uint2 gathers (NEUTRAL -> not issue-bound).
// R15: NB 256->1024. R16: spill-proof 2-threads/node GEMMs.
// R17 (REGRESSED): 8-slot batches = 50% clamped-duplicate gathers.
// R18: clean/tail split, agg32 16-edge units. 343us (best).
// R19: agg64 NODE-PAIR INTERLEAVE. Per-wave MLP was capped at 4 real
// loads in flight (next node's loads sit after this node's waitcnt in
// program order; ~1100cy/node mostly exposed latency). Adjacent CSR
// nodes share the staged window -> issue A's 4 + B's 4 gathers before
// one waitcnt: 8 REAL loads in flight, zero waste (R17's lesson).
// Unequal degrees: predicated mixed batch + span leftovers; pair range
// >128 edges falls back to solo path (exact).

#define NB   1024       // dst buckets (128 nodes each; supports N < 131072)
#define BSH  7          // log2(nodes per bucket)
#define BMASK 127
#define BN   128        // nodes per bucket
#define PBLK 1024       // partition blocks
#define FIXP_SCALE 1048576.0f   // 2^20
#define FIXP_MASK  ((1ULL << 40) - 1)

__device__ __forceinline__ int lower_bound_i(const int* __restrict__ a, int n, int v) {
    int lo = 0, hi = n;
    while (lo < hi) {
        int m = (lo + hi) >> 1;
        if (a[m] < v) lo = m + 1; else hi = m;
    }
    return lo;
}

// A1: per-block histogram over NB dst-buckets (LDS atomics only)
__global__ __launch_bounds__(256) void k_bhist(const int* __restrict__ dst,
                                               int* __restrict__ hcnt, int e) {
    __shared__ int hist[NB];
    int tid = threadIdx.x, blk = blockIdx.x;
#pragma unroll
    for (int b = 0; b < NB / 256; ++b) hist[tid + 256 * b] = 0;
    __syncthreads();
    int chunk = (e + PBLK - 1) / PBLK;
    int lo = blk * chunk, hi = min(e, lo + chunk);
    for (int i = lo + tid; i < hi; i += 256)
        atomicAdd(&hist[dst[i] >> BSH], 1);
    __syncthreads();
#pragma unroll
    for (int b = 0; b < NB / 256; ++b) {
        int bb = tid + 256 * b;
        hcnt[bb * PBLK + blk] = hist[bb];   // [bucket][block] layout
    }
}

// A2a: per-bucket exclusive scan across the PBLK block-counts (in place) + totals
__global__ __launch_bounds__(256) void k_bscan(int* __restrict__ hcnt,
                                               int* __restrict__ btot) {
    __shared__ int s[256];
    int b = blockIdx.x, tid = threadIdx.x;
    int* row = hcnt + b * PBLK;
    int a0 = row[4 * tid], a1 = row[4 * tid + 1], a2 = row[4 * tid + 2], a3 = row[4 * tid + 3];
    int tsum = a0 + a1 + a2 + a3;
    s[tid] = tsum;
    __syncthreads();
    for (int off = 1; off < 256; off <<= 1) {
        int t = (tid >= off) ? s[tid - off] : 0;
        __syncthreads();
        s[tid] += t;
        __syncthreads();
    }
    int ex = s[tid] - tsum;
    row[4 * tid] = ex;
    row[4 * tid + 1] = ex + a0;
    row[4 * tid + 2] = ex + a0 + a1;
    row[4 * tid + 3] = ex + a0 + a1 + a2;
    if (tid == 255) btot[b] = s[255];
}

// A2b: scan NB bucket totals -> bucket_base[NB+1]; also rowptr[n]=e
__global__ __launch_bounds__(256) void k_bbase(const int* __restrict__ btot,
                                               int* __restrict__ bbase,
                                               int* __restrict__ rowptr, int n, int e) {
    __shared__ int s[256];
    int tid = threadIdx.x;
    int a0 = btot[4 * tid], a1 = btot[4 * tid + 1],
        a2 = btot[4 * tid + 2], a3 = btot[4 * tid + 3];
    int tsum = a0 + a1 + a2 + a3;
    s[tid] = tsum;
    __syncthreads();
    for (int off = 1; off < 256; off <<= 1) {
        int t = (tid >= off) ? s[tid - off] : 0;
        __syncthreads();
        s[tid] += t;
        __syncthreads();
    }
    int ex = s[tid] - tsum;
    bbase[4 * tid] = ex;
    bbase[4 * tid + 1] = ex + a0;
    bbase[4 * tid + 2] = ex + a0 + a1;
    bbase[4 * tid + 3] = ex + a0 + a1 + a2;
    if (tid == 255) bbase[NB] = s[255];   // == e
    if (tid == 0) rowptr[n] = e;
}

// A3: partition edges into buckets; pos from LDS cursor (no global atomics)
__global__ __launch_bounds__(256) void k_bpart(const int* __restrict__ src,
                                               const int* __restrict__ dst,
                                               const float* __restrict__ ew,
                                               const int* __restrict__ hcnt,
                                               const int* __restrict__ bbase,
                                               int2* __restrict__ bedge, int e) {
    __shared__ int cur[NB];
    int tid = threadIdx.x, blk = blockIdx.x;
#pragma unroll
    for (int b = 0; b < NB / 256; ++b) {
        int bb = tid + 256 * b;
        cur[bb] = bbase[bb] + hcnt[bb * PBLK + blk];
    }
    __syncthreads();
    int chunk = (e + PBLK - 1) / PBLK;
    int lo = blk * chunk, hi = min(e, lo + chunk);
    for (int i = lo + tid; i < hi; i += 256) {
        int d = dst[i];
        int pos = atomicAdd(&cur[d >> BSH], 1);          // LDS atomic
        bedge[pos] = make_int2(src[i] | ((d & BMASK) << 17), __float_as_int(ew[i]));
    }
}

// B: per-bucket (BN=128 nodes): LDS packed cnt + fixp sum(ew) -> dis,
// rowptr, then scatter (src, ew*dis[d]) grouped per node into em.
// Fused hs = fp16(dis*x) for this bucket's nodes. No global atomics.
__global__ __launch_bounds__(256) void k_bucket(const int2* __restrict__ bedge,
                                                const int* __restrict__ bbase,
                                                float* __restrict__ dis,
                                                int* __restrict__ rowptr,
                                                int2* __restrict__ em,
                                                const float* __restrict__ x,
                                                __half* __restrict__ hs, int n) {
    __shared__ unsigned long long pk[BN];
    __shared__ int cnt[BN];
    __shared__ int scn[BN];
    __shared__ float sdis[BN];
    __shared__ int cur[BN];
    int b = blockIdx.x, tid = threadIdx.x;
    int e0 = bbase[b], e1 = bbase[b + 1];
    if (tid < BN) pk[tid] = 0ULL;
    __syncthreads();
    for (int i = e0 + tid; i < e1; i += 256) {
        int2 v = bedge[i];
        int dlo = (v.x >> 17) & BMASK;
        unsigned long long p =
            (1ULL << 40) | (unsigned long long)(__int_as_float(v.y) * FIXP_SCALE);
        atomicAdd(&pk[dlo], p);                          // LDS atomic
    }
    __syncthreads();
    if (tid < BN) {
        unsigned long long v = pk[tid];
        int c = (int)(v >> 40);
        cnt[tid] = c; scn[tid] = c;
        sdis[tid] = rsqrtf(1.0f + (float)(v & FIXP_MASK) * (1.0f / FIXP_SCALE));
    }
    __syncthreads();
    // BN-entry inclusive scan (all threads hit the barriers)
    for (int off = 1; off < BN; off <<= 1) {
        int v0 = (tid >= off && tid < BN) ? scn[tid - off] : 0;
        __syncthreads();
        if (tid < BN) scn[tid] += v0;
        __syncthreads();
    }
    if (tid < BN) {
        int rb = e0 + scn[tid] - cnt[tid];               // exclusive
        cur[tid] = rb;
        int node = (b << BSH) + tid;
        if (node < n) { rowptr[node] = rb; dis[node] = sdis[tid]; }
    }
    __syncthreads();
    for (int i = e0 + tid; i < e1; i += 256) {
        int2 v = bedge[i];
        int dlo = (v.x >> 17) & BMASK;
        int pos = atomicAdd(&cur[dlo], 1);               // LDS atomic
        float w = __int_as_float(v.y) * sdis[dlo];
        em[pos] = make_int2(v.x & 0x1FFFF, __float_as_int(w));
    }
    // fused layer-1 pre-scale: hs = fp16(dis * x) for nodes of this bucket
    int nodebase = b << BSH;
    int nloc = n - nodebase; if (nloc > BN) nloc = BN;
    if (nloc > 0) {
        const float2* x2 = (const float2*)(x + (size_t)nodebase * 32);
        __half2* hs2 = (__half2*)(hs + (size_t)nodebase * 32);
        int total2 = nloc * 16;                    // 16 float2 per 32-ch row
        for (int i = tid; i < total2; i += 256) {
            float d = sdis[i >> 4];
            float2 v = x2[i];
            hs2[i] = __float22half2_rn(make_float2(v.x * d, v.y * d));
        }
    }
}

__device__ __forceinline__ float2 cvt_pair(unsigned int u) {
    __half2 h2 = *(__half2*)&u;
    return __half22float2(h2);
}

// R18: pure 32-ch aggregate, 4ch/lane, 16-edge units (2 slots) with
// clean/tail split. y0 = sum_e w_e hs[src] + di*hs[node].
__global__ __launch_bounds__(256, 4) void k_agg32(const __half* __restrict__ hs,
                                                  const int2* __restrict__ em,
                                                  const int* __restrict__ rowptr,
                                                  const float* __restrict__ dis,
                                                  __half* __restrict__ y0, int n) {
    __shared__ __align__(8) int2 sme[4][128];
    int lane = threadIdx.x & 63, wv = threadIdx.x >> 6;
    int c = lane & 7, oct = lane >> 3;
    const uint2* h64 = (const uint2*)hs;      // 8 uint2 per 32-ch row
    int wid = (blockIdx.x * blockDim.x + threadIdx.x) >> 6;
    int n0 = wid * 8;
    if (n0 >= n) return;
    int cnt = min(8, n - n0);
    int rp = 0;
    if (lane <= cnt) rp = rowptr[n0 + lane];
    int hiw = __shfl(rp, cnt, 64);            // end of wave's edge range
    int wlo = 0, whi = 0;                     // staged window [wlo, whi)
    for (int k = 0; k < cnt; ++k) {
        int node = n0 + k;
        int lo = __shfl(rp, k, 64), hi = __shfl(rp, k + 1, 64);
        float2 a0 = make_float2(0.0f, 0.0f), a1 = make_float2(0.0f, 0.0f);
        if (oct == 0) {
            float di = dis[node];
            uint2 sh = h64[(unsigned)(node * 8 + c)];
            float2 f0 = cvt_pair(sh.x), f1 = cvt_pair(sh.y);
            a0.x = di * f0.x; a0.y = di * f0.y;          // self: di^2*x = di*hs
            a1.x = di * f1.x; a1.y = di * f1.y;
        }
        int idx = lo;
        while (idx < hi) {
            if (idx >= whi) {                 // refill (wave-uniform)
                int i0 = idx + lane;
                if (i0 < hiw) sme[wv][lane] = em[i0];
                int i1 = i0 + 64;
                if (i1 < hiw) sme[wv][lane + 64] = em[i1];
                wlo = idx; whi = idx + 128;
            }
            int base = idx - wlo;
            int take = min(hi, whi) - idx;    // 1..128 edges this pass
            int g = 0;
            // clean 16-edge batches: no predication, no clamped dups
            for (; g + 16 <= take; g += 16) {
                int2 ev[2]; uint2 hv[2];
#pragma unroll
                for (int t = 0; t < 2; ++t)
                    ev[t] = sme[wv][base + g + 8 * t + oct];      // 8-way bcast
#pragma unroll
                for (int t = 0; t < 2; ++t)
                    hv[t] = h64[(unsigned)(ev[t].x * 8 + c)];
#pragma unroll
                for (int t = 0; t < 2; ++t) {
                    float ww = __int_as_float(ev[t].y);
                    float2 f0 = cvt_pair(hv[t].x), f1 = cvt_pair(hv[t].y);
                    a0.x = fmaf(ww, f0.x, a0.x);
                    a0.y = fmaf(ww, f0.y, a0.y);
                    a1.x = fmaf(ww, f1.x, a1.x);
                    a1.y = fmaf(ww, f1.y, a1.y);
                }
            }
            if (g < take) {                   // predicated tail (<=15 edges)
                int2 ev[2]; uint2 hv[2]; int pr[2];
#pragma unroll
                for (int t = 0; t < 2; ++t) {
                    int p = g + 8 * t + oct;
                    pr[t] = p < take;
                    int pc = pr[t] ? p : 0;               // clamp: stay in window
                    ev[t] = sme[wv][base + pc];
                }
#pragma unroll
                for (int t = 0; t < 2; ++t)
                    hv[t] = h64[(unsigned)(ev[t].x * 8 + c)];
#pragma unroll
                for (int t = 0; t < 2; ++t) {
                    float ww = pr[t] ? __int_as_float(ev[t].y) : 0.0f;
                    float2 f0 = cvt_pair(hv[t].x), f1 = cvt_pair(hv[t].y);
                    a0.x = fmaf(ww, f0.x, a0.x);
                    a0.y = fmaf(ww, f0.y, a0.y);
                    a1.x = fmaf(ww, f1.x, a1.x);
                    a1.y = fmaf(ww, f1.y, a1.y);
                }
            }
            idx += take;
        }
        // reduce across octs
        a0.x += __shfl_down(a0.x, 32, 64); a0.y += __shfl_down(a0.y, 32, 64);
        a1.x += __shfl_down(a1.x, 32, 64); a1.y += __shfl_down(a1.y, 32, 64);
        a0.x += __shfl_down(a0.x, 16, 64); a0.y += __shfl_down(a0.y, 16, 64);
        a1.x += __shfl_down(a1.x, 16, 64); a1.y += __shfl_down(a1.y, 16, 64);
        a0.x += __shfl_down(a0.x, 8, 64);  a0.y += __shfl_down(a0.y, 8, 64);
        a1.x += __shfl_down(a1.x, 8, 64);  a1.y += __shfl_down(a1.y, 8, 64);
        if (oct == 0) {
            uint2 o;
            __half2 p0 = __float22half2_rn(make_float2(a0.x, a0.y));
            __half2 p1 = __float22half2_rn(make_float2(a1.x, a1.y));
            o.x = *(unsigned int*)&p0; o.y = *(unsigned int*)&p1;
            ((uint2*)y0)[(size_t)node * 8 + c] = o;
        }
    }
}

// R16: h1' = silu(y0 @ W1 + b1) * dis.  2 THREADS PER NODE.
__global__ __launch_bounds__(256, 4) void k_mm32act(const __half* __restrict__ y0,
                                                    const float* __restrict__ W,
                                                    const float* __restrict__ bias,
                                                    const float* __restrict__ dis,
                                                    __half* __restrict__ out, int n) {
    __shared__ __align__(16) float sw[32 * 64 + 64];
#pragma unroll
    for (int i = 0; i < 8; ++i)
        sw[threadIdx.x + 256 * i] = W[threadIdx.x + 256 * i];
    if (threadIdx.x < 64) sw[2048 + threadIdx.x] = bias[threadIdx.x];
    __syncthreads();
    int idx = blockIdx.x * 256 + threadIdx.x;
    int node = idx >> 1, half = idx & 1;
    if (node >= n) return;
    const uint4* yrow = (const uint4*)(y0 + (size_t)node * 32);
    float o[32];
#pragma unroll
    for (int j = 0; j < 32; ++j) o[j] = sw[2048 + half * 32 + j];
#pragma unroll
    for (int kb = 0; kb < 2; ++kb) {           // 2 chunks of 16 channels
        uint4 ya = yrow[2 * kb], yb = yrow[2 * kb + 1];
        unsigned int yw[8] = {ya.x, ya.y, ya.z, ya.w, yb.x, yb.y, yb.z, yb.w};
#pragma unroll
        for (int k2 = 0; k2 < 8; ++k2) {
            float2 yk = cvt_pair(yw[k2]);
            int k = kb * 16 + 2 * k2;
            const float4* r0 = (const float4*)&sw[k * 64 + half * 32];
            const float4* r1 = (const float4*)&sw[(k + 1) * 64 + half * 32];
#pragma unroll
            for (int j4 = 0; j4 < 8; ++j4) {
                float4 w0 = r0[j4];
                float4 w1 = r1[j4];
                o[4 * j4 + 0] = fmaf(yk.y, w1.x, fmaf(yk.x, w0.x, o[4 * j4 + 0]));
                o[4 * j4 + 1] = fmaf(yk.y, w1.y, fmaf(yk.x, w0.y, o[4 * j4 + 1]));
                o[4 * j4 + 2] = fmaf(yk.y, w1.z, fmaf(yk.x, w0.z, o[4 * j4 + 2]));
                o[4 * j4 + 3] = fmaf(yk.y, w1.w, fmaf(yk.x, w0.w, o[4 * j4 + 3]));
            }
        }
    }
    float dsc = dis[node];
    __half2* orow = (__half2*)(out + (size_t)node * 64 + half * 32);
#pragma unroll
    for (int j2 = 0; j2 < 16; ++j2) {
        float ox = o[2 * j2], oy = o[2 * j2 + 1];
        ox = ox / (1.0f + __expf(-ox)) * dsc;
        oy = oy / (1.0f + __expf(-oy)) * dsc;
        orow[j2] = __float22half2_rn(make_float2(ox, oy));
    }
}

// R16: z = y @ W  (N x 64 fp16 in, 64x64 fp32 W in LDS, N x 64 fp16 out).
// 2 THREADS PER NODE (half = 32 outputs each); spill-proof.
__global__ __launch_bounds__(256, 4) void k_mm64(const __half* __restrict__ y,
                                                 const float* __restrict__ W,
                                                 __half* __restrict__ z, int n) {
    __shared__ __align__(16) float sw[64 * 64];     // 16 KB
#pragma unroll
    for (int i = 0; i < 16; ++i)
        sw[threadIdx.x + 256 * i] = W[threadIdx.x + 256 * i];
    __syncthreads();
    int idx = blockIdx.x * 256 + threadIdx.x;
    int node = idx >> 1, half = idx & 1;
    if (node >= n) return;
    const uint4* yrow = (const uint4*)(y + (size_t)node * 64);
    float o[32];
#pragma unroll
    for (int j = 0; j < 32; ++j) o[j] = 0.0f;
#pragma unroll
    for (int kb = 0; kb < 4; ++kb) {           // 4 chunks of 16 channels
        uint4 ya = yrow[2 * kb], yb = yrow[2 * kb + 1];
        unsigned int yw[8] = {ya.x, ya.y, ya.z, ya.w, yb.x, yb.y, yb.z, yb.w};
#pragma unroll
        for (int k2 = 0; k2 < 8; ++k2) {
            float2 yk = cvt_pair(yw[k2]);
            int k = kb * 16 + 2 * k2;
            const float4* r0 = (const float4*)&sw[k * 64 + half * 32];
            const float4* r1 = (const float4*)&sw[(k + 1) * 64 + half * 32];
#pragma unroll
            for (int j4 = 0; j4 < 8; ++j4) {
                float4 w0 = r0[j4];
                float4 w1 = r1[j4];
                o[4 * j4 + 0] = fmaf(yk.y, w1.x, fmaf(yk.x, w0.x, o[4 * j4 + 0]));
                o[4 * j4 + 1] = fmaf(yk.y, w1.y, fmaf(yk.x, w0.y, o[4 * j4 + 1]));
                o[4 * j4 + 2] = fmaf(yk.y, w1.z, fmaf(yk.x, w0.z, o[4 * j4 + 2]));
                o[4 * j4 + 3] = fmaf(yk.y, w1.w, fmaf(yk.x, w0.w, o[4 * j4 + 3]));
            }
        }
    }
    __half2* zrow = (__half2*)(z + (size_t)node * 64 + half * 32);
#pragma unroll
    for (int j2 = 0; j2 < 16; ++j2)
        zrow[j2] = __float22half2_rn(make_float2(o[2 * j2], o[2 * j2 + 1]));
}

// ---- R19 agg64 helpers: span = process [idx,hi) fully inside window ----
__device__ __forceinline__ void agg64_span(const uint2* __restrict__ h64,
                                           const int2* smerow, int c, int quarter,
                                           int wlo, int idx, int hi,
                                           float2& a0, float2& a1) {
    while (idx < hi) {
        int g = idx - wlo;
        int take = hi - idx;
        if (take >= 16) {                     // clean batch
            int2 ev[4]; uint2 hv[4];
#pragma unroll
            for (int t = 0; t < 4; ++t)
                ev[t] = smerow[g + 4 * t + quarter];
#pragma unroll
            for (int t = 0; t < 4; ++t)
                hv[t] = h64[(unsigned)(ev[t].x * 16 + c)];
#pragma unroll
            for (int t = 0; t < 4; ++t) {
                float ww = __int_as_float(ev[t].y);
                float2 f0 = cvt_pair(hv[t].x), f1 = cvt_pair(hv[t].y);
                a0.x = fmaf(ww, f0.x, a0.x); a0.y = fmaf(ww, f0.y, a0.y);
                a1.x = fmaf(ww, f1.x, a1.x); a1.y = fmaf(ww, f1.y, a1.y);
            }
            idx += 16;
        } else {                              // predicated tail
            int2 ev[4]; uint2 hv[4]; int pr[4];
#pragma unroll
            for (int t = 0; t < 4; ++t) {
                int p = 4 * t + quarter;
                pr[t] = p < take;
                ev[t] = smerow[g + (pr[t] ? p : 0)];
            }
#pragma unroll
            for (int t = 0; t < 4; ++t)
                hv[t] = h64[(unsigned)(ev[t].x * 16 + c)];
#pragma unroll
            for (int t = 0; t < 4; ++t) {
                float ww = pr[t] ? __int_as_float(ev[t].y) : 0.0f;
                float2 f0 = cvt_pair(hv[t].x), f1 = cvt_pair(hv[t].y);
                a0.x = fmaf(ww, f0.x, a0.x); a0.y = fmaf(ww, f0.y, a0.y);
                a1.x = fmaf(ww, f1.x, a1.x); a1.y = fmaf(ww, f1.y, a1.y);
            }
            idx = hi;
        }
    }
}

// solo = process [idx,hi) with window refill (fallback / odd node)
__device__ __forceinline__ void agg64_solo(const uint2* __restrict__ h64,
                                           int2* smerow, const int2* __restrict__ em,
                                           int lane, int c, int quarter, int hiw,
                                           int& wlo, int& whi, int idx, int hi,
                                           float2& a0, float2& a1) {
    while (idx < hi) {
        if (idx >= whi) {                     // refill (wave-uniform)
            int i0 = idx + lane;
            if (i0 < hiw) smerow[lane] = em[i0];
            int i1 = i0 + 64;
            if (i1 < hiw) smerow[lane + 64] = em[i1];
            wlo = idx; whi = idx + 128;
        }
        int stop = min(hi, whi);
        agg64_span(h64, smerow, c, quarter, wlo, idx, stop, a0, a1);
        idx = stop;
    }
}

// R19: lean 64-ch aggregate, 4ch/lane, NODE-PAIR interleave: 8 real
// gathers in flight per wait (A's 4 + B's 4, adjacent CSR nodes).
// out = [di*] silu( sum_e w_e z[src] + di*z[node] + bias ).
template <bool SCALE, typename OUT>
__global__ __launch_bounds__(256, 4) void k_agg64(const __half* __restrict__ z,
                                                  const int2* __restrict__ em,
                                                  const int* __restrict__ rowptr,
                                                  const float* __restrict__ dis,
                                                  const float* __restrict__ bias,
                                                  OUT* __restrict__ out, int n) {
    __shared__ __align__(8) int2 sme[4][128];
    int lane = threadIdx.x & 63, wv = threadIdx.x >> 6;
    int c = lane & 15, quarter = lane >> 4;
    const uint2* h64 = (const uint2*)z;       // 16 uint2 per 64-ch row
    int2* smerow = sme[wv];
    float4 bv4 = ((const float4*)bias)[c];
    int wid = (blockIdx.x * blockDim.x + threadIdx.x) >> 6;
    int n0 = wid * 8;
    if (n0 >= n) return;
    int cnt = min(8, n - n0);
    int rp = 0;
    if (lane <= cnt) rp = rowptr[n0 + lane];
    int hiw = __shfl(rp, cnt, 64);
    int wlo = 0, whi = 0;
    int k = 0;
    for (; k + 1 < cnt; k += 2) {
        int nodeA = n0 + k, nodeB = nodeA + 1;
        int loA = __shfl(rp, k, 64);
        int hiA = __shfl(rp, k + 1, 64);
        int hiB = __shfl(rp, k + 2, 64);
        float diA = 0.0f, diB = 0.0f;
        float2 a0A = make_float2(0.f, 0.f), a1A = make_float2(0.f, 0.f);
        float2 a0B = make_float2(0.f, 0.f), a1B = make_float2(0.f, 0.f);
        if (quarter == 0) {
            diA = dis[nodeA]; diB = dis[nodeB];
            uint2 sA = h64[(unsigned)(nodeA * 16 + c)];
            uint2 sB = h64[(unsigned)(nodeB * 16 + c)];
            float2 fA0 = cvt_pair(sA.x), fA1 = cvt_pair(sA.y);
            float2 fB0 = cvt_pair(sB.x), fB1 = cvt_pair(sB.y);
            a0A.x = diA * fA0.x; a0A.y = diA * fA0.y;    // self-loop terms
            a1A.x = diA * fA1.x; a1A.y = diA * fA1.y;
            a0B.x = diB * fB0.x; a0B.y = diB * fB0.y;
            a1B.x = diB * fB1.x; a1B.y = diB * fB1.y;
        }
        if (hiB > whi && hiB - loA <= 128) {  // refill window at loA
            int i0 = loA + lane;
            if (i0 < hiw) smerow[lane] = em[i0];
            int i1 = i0 + 64;
            if (i1 < hiw) smerow[lane + 64] = em[i1];
            wlo = loA; whi = loA + 128;
        }
        if (hiB <= whi) {
            // paired path: both ranges inside window; interleave batches
            int idxA = loA, idxB = hiA;
            while (idxA < hiA && idxB < hiB) {
                int tA = min(hiA - idxA, 16), tB = min(hiB - idxB, 16);
                int gA = idxA - wlo, gB = idxB - wlo;
                if (tA == 16 && tB == 16) {   // clean-clean: no predication
                    int2 ev[8]; uint2 hv[8];
#pragma unroll
                    for (int t = 0; t < 4; ++t) {
                        ev[t]     = smerow[gA + 4 * t + quarter];
                        ev[t + 4] = smerow[gB + 4 * t + quarter];
                    }
#pragma unroll
                    for (int t = 0; t < 8; ++t)
                        hv[t] = h64[(unsigned)(ev[t].x * 16 + c)];  // 8 in flight
#pragma unroll
                    for (int t = 0; t < 4; ++t) {
                        float wwA = __int_as_float(ev[t].y);
                        float2 f0 = cvt_pair(hv[t].x), f1 = cvt_pair(hv[t].y);
                        a0A.x = fmaf(wwA, f0.x, a0A.x); a0A.y = fmaf(wwA, f0.y, a0A.y);
                        a1A.x = fmaf(wwA, f1.x, a1A.x); a1A.y = fmaf(wwA, f1.y, a1A.y);
                        float wwB = __int_as_float(ev[t + 4].y);
                        float2 g0 = cvt_pair(hv[t + 4].x), g1 = cvt_pair(hv[t + 4].y);
                        a0B.x = fmaf(wwB, g0.x, a0B.x); a0B.y = fmaf(wwB, g0.y, a0B.y);
                        a1B.x = fmaf(wwB, g1.x, a1B.x); a1B.y = fmaf(wwB, g1.y, a1B.y);
                    }
                } else {                      // mixed: predicated both
                    int2 ev[8]; uint2 hv[8]; int pr[8];
#pragma unroll
                    for (int t = 0; t < 4; ++t) {
                        int p = 4 * t + quarter;
                        pr[t] = p < tA;
                        ev[t] = smerow[gA + (pr[t] ? p : 0)];
                        pr[t + 4] = p < tB;
                        ev[t + 4] = smerow[gB + (pr[t + 4] ? p : 0)];
                    }
#pragma unroll
                    for (int t = 0; t < 8; ++t)
                        hv[t] = h64[(unsigned)(ev[t].x * 16 + c)];
#pragma unroll
                    for (int t = 0; t < 4; ++t) {
                        float wwA = pr[t] ? __int_as_float(ev[t].y) : 0.0f;
                        float2 f0 = cvt_pair(hv[t].x), f1 = cvt_pair(hv[t].y);
                        a0A.x = fmaf(wwA, f0.x, a0A.x); a0A.y = fmaf(wwA, f0.y, a0A.y);
                        a1A.x = fmaf(wwA, f1.x, a1A.x); a1A.y = fmaf(wwA, f1.y, a1A.y);
                        float wwB = pr[t + 4] ? __int_as_float(ev[t + 4].y) : 0.0f;
                        float2 g0 = cvt_pair(hv[t + 4].x), g1 = cvt_pair(hv[t + 4].y);
                        a0B.x = fmaf(wwB, g0.x, a0B.x); a0B.y = fmaf(wwB, g0.y, a0B.y);
                        a1B.x = fmaf(wwB, g1.x, a1B.x); a1B.y = fmaf(wwB, g1.y, a1B.y);
                    }
                }
                idxA += tA; idxB += tB;
            }
            if (idxA < hiA) agg64_span(h64, smerow, c, quarter, wlo, idxA, hiA, a0A, a1A);
            if (idxB < hiB) agg64_span(h64, smerow, c, quarter, wlo, idxB, hiB, a0B, a1B);
        } else {
            // rare: pair spans >128 edges -> sequential solo (exact)
            agg64_solo(h64, smerow, em, lane, c, quarter, hiw, wlo, whi, loA, hiA, a0A, a1A);
            agg64_solo(h64, smerow, em, lane, c, quarter, hiw, wlo, whi, hiA, hiB, a0B, a1B);
        }
        // interleaved cross-quarter reduce for both nodes
        a0A.x += __shfl_down(a0A.x, 32, 64); a0A.y += __shfl_down(a0A.y, 32, 64);
        a1A.x += __shfl_down(a1A.x, 32, 64); a1A.y += __shfl_down(a1A.y, 32, 64);
        a0B.x += __shfl_down(a0B.x, 32, 64); a0B.y += __shfl_down(a0B.y, 32, 64);
        a1B.x += __shfl_down(a1B.x, 32, 64); a1B.y += __shfl_down(a1B.y, 32, 64);
        a0A.x += __shfl_down(a0A.x, 16, 64); a0A.y += __shfl_down(a0A.y, 16, 64);
        a1A.x += __shfl_down(a1A.x, 16, 64); a1A.y += __shfl_down(a1A.y, 16, 64);
        a0B.x += __shfl_down(a0B.x, 16, 64); a0B.y += __shfl_down(a0B.y, 16, 64);
        a1B.x += __shfl_down(a1B.x, 16, 64); a1B.y += __shfl_down(a1B.y, 16, 64);
        if (quarter == 0) {
            float ox = a0A.x + bv4.x, oy = a0A.y + bv4.y;
            float oz = a1A.x + bv4.z, ow = a1A.y + bv4.w;
            ox = ox / (1.0f + __expf(-ox));
            oy = oy / (1.0f + __expf(-oy));
            oz = oz / (1.0f + __expf(-oz));
            ow = ow / (1.0f + __expf(-ow));
            if (SCALE) { ox *= diA; oy *= diA; oz *= diA; ow *= diA; }
            float px = a0B.x + bv4.x, py = a0B.y + bv4.y;
            float pz = a1B.x + bv4.z, pw = a1B.y + bv4.w;
            px = px / (1.0f + __expf(-px));
            py = py / (1.0f + __expf(-py));
            pz = pz / (1.0f + __expf(-pz));
            pw = pw / (1.0f + __expf(-pw));
            if (SCALE) { px *= diB; py *= diB; pz *= diB; pw *= diB; }
            if (sizeof(OUT) == 2) {
                uint2 oA, oB;
                __half2 q0 = __float22half2_rn(make_float2(ox, oy));
                __half2 q1 = __float22half2_rn(make_float2(oz, ow));
                oA.x = *(unsigned int*)&q0; oA.y = *(unsigned int*)&q1;
                __half2 r0 = __float22half2_rn(make_float2(px, py));
                __half2 r1 = __float22half2_rn(make_float2(pz, pw));
                oB.x = *(unsigned int*)&r0; oB.y = *(unsigned int*)&r1;
                ((uint2*)out)[(size_t)nodeA * 16 + c] = oA;
                ((uint2*)out)[(size_t)nodeB * 16 + c] = oB;
            } else {
                ((float4*)out)[(size_t)nodeA * 16 + c] = make_float4(ox, oy, oz, ow);
                ((float4*)out)[(size_t)nodeB * 16 + c] = make_float4(px, py, pz, pw);
            }
        }
    }
    if (k < cnt) {                            // odd last node: solo path
        int node = n0 + k;
        int lo = __shfl(rp, k, 64), hi = __shfl(rp, k + 1, 64);
        float di = 0.0f;
        float2 a0 = make_float2(0.f, 0.f), a1 = make_float2(0.f, 0.f);
        if (quarter == 0) {
            di = dis[node];
            uint2 sh = h64[(unsigned)(node * 16 + c)];
            float2 f0 = cvt_pair(sh.x), f1 = cvt_pair(sh.y);
            a0.x = di * f0.x; a0.y = di * f0.y;
            a1.x = di * f1.x; a1.y = di * f1.y;
        }
        agg64_solo(h64, smerow, em, lane, c, quarter, hiw, wlo, whi, lo, hi, a0, a1);
        a0.x += __shfl_down(a0.x, 32, 64); a0.y += __shfl_down(a0.y, 32, 64);
        a1.x += __shfl_down(a1.x, 32, 64); a1.y += __shfl_down(a1.y, 32, 64);
        a0.x += __shfl_down(a0.x, 16, 64); a0.y += __shfl_down(a0.y, 16, 64);
        a1.x += __shfl_down(a1.x, 16, 64); a1.y += __shfl_down(a1.y, 16, 64);
        if (quarter == 0) {
            float ox = a0.x + bv4.x, oy = a0.y + bv4.y;
            float oz = a1.x + bv4.z, ow = a1.y + bv4.w;
            ox = ox / (1.0f + __expf(-ox));
            oy = oy / (1.0f + __expf(-oy));
            oz = oz / (1.0f + __expf(-oz));
            ow = ow / (1.0f + __expf(-ow));
            if (SCALE) { ox *= di; oy *= di; oz *= di; ow *= di; }
            if (sizeof(OUT) == 2) {
                uint2 o;
                __half2 p0 = __float22half2_rn(make_float2(ox, oy));
                __half2 p1 = __float22half2_rn(make_float2(oz, ow));
                o.x = *(unsigned int*)&p0; o.y = *(unsigned int*)&p1;
                ((uint2*)out)[(size_t)node * 16 + c] = o;
            } else {
                ((float4*)out)[(size_t)node * 16 + c] = make_float4(ox, oy, oz, ow);
            }
        }
    }
}

// pool phase 1: 128-row chunks, segment-flush atomics into acc[G*64]
__global__ void k_pool_partial(const float* __restrict__ h, const int* __restrict__ batch,
                               float* __restrict__ acc, int n) {
    int c = threadIdx.x & 63, r = threadIdx.x >> 6;
    int base = blockIdx.x * 128;
    int end = base + 128; if (end > n) end = n;
    float part = 0.0f;
    int cur = -1;
    for (int i = base + r; i < end; i += 4) {
        int g = batch[i];
        if (g != cur) {
            if (cur >= 0) atomicAdd(&acc[cur * 64 + c], part);
            part = 0.0f;
            cur = g;
        }
        part += h[(size_t)i * 64 + c];
    }
    if (cur >= 0) atomicAdd(&acc[cur * 64 + c], part);
}

// pool phase 2: divide by per-graph count
__global__ void k_pool_final(const float* __restrict__ acc, const int* __restrict__ batch,
                             float* __restrict__ out, int n) {
    int idx = blockIdx.x * blockDim.x + threadIdx.x;   // G*64 threads
    int g = idx >> 6;
    int lo = lower_bound_i(batch, n, g);
    int hi = lower_bound_i(batch, n, g + 1);
    int cnt = hi - lo;
    out[idx] = acc[idx] / (float)(cnt > 0 ? cnt : 1);
}

extern "C" void kernel_launch(void* const* d_in, const int* in_sizes, int n_in,
                              void* d_out, int out_size, void* d_ws, size_t ws_size,
                              hipStream_t stream) {
    const float* x   = (const float*)d_in[0];
    const float* ew  = (const float*)d_in[1];
    const float* W1  = (const float*)d_in[2];
    const float* b1  = (const float*)d_in[3];
    const float* W2  = (const float*)d_in[4];
    const float* b2  = (const float*)d_in[5];
    const float* W3  = (const float*)d_in[6];
    const float* b3  = (const float*)d_in[7];
    const int*   eidx  = (const int*)d_in[8];
    const int*   batch = (const int*)d_in[9];
    float* out = (float*)d_out;

    const int E = in_sizes[1];       // 1,600,000
    const int N = in_sizes[9];       // 100,000 (< 131072: fits 17-bit src pack)
    const int G = 64;
    const int* src = eidx;
    const int* dst = eidx + E;

    // workspace: A/B (fp16 features) double as CSR-build scratch
    // (bedge in A: E*8B == N*64*2B exactly; hcnt/btot in B: 4MB+4KB);
    // C holds the fp16 y0 aggregate early, then the final fp32 layer.
    char* p = (char*)d_ws;
    __half* A     = (__half*)p;                p += (size_t)N * 64 * sizeof(__half);
    __half* B     = (__half*)p;                p += (size_t)N * 64 * sizeof(__half);
    float* C      = (float*)p;                 p += (size_t)N * 64 * sizeof(float);
    float* dis    = (float*)p;                 p += (size_t)N * sizeof(float);
    int*   rowptr = (int*)p;                   p += (size_t)(N + 1) * sizeof(int);
    int*   bbase  = (int*)p;                   p += (size_t)(NB + 1) * sizeof(int);
    float* acc    = (float*)p;                 p += (size_t)G * 64 * sizeof(float);
    p = (char*)(((uintptr_t)p + 7) & ~(uintptr_t)7);
    int2*  em     = (int2*)p;                  // E entries, 8B

    int2* bedge = (int2*)A;                    // E*8B == N*64*2B
    int*  hcnt  = (int*)B;                     // NB*PBLK*4B = 4MB
    int*  btot  = (int*)B + NB * PBLK;         // NB ints

    const int BT = 256;
    const int WAVES = (N + 7) / 8;             // 12500 waves, 8 contiguous nodes each
    const int AGG_BLOCKS = (WAVES + 3) / 4;    // 3125
    const int MM_BLOCKS = (2 * N + 255) / 256; // 782, 2 threads per node

    // --- CSR build: LDS counting sort, zero global atomics ---
    k_bhist<<<PBLK, 256, 0, stream>>>(dst, hcnt, E);
    k_bscan<<<NB, 256, 0, stream>>>(hcnt, btot);
    k_bbase<<<1, 256, 0, stream>>>(btot, bbase, rowptr, N, E);
    k_bpart<<<PBLK, 256, 0, stream>>>(src, dst, ew, hcnt, bbase, bedge, E);
    // k_bucket also emits hs = fp16(dis*x) into B (hcnt scratch dead here)
    k_bucket<<<NB, 256, 0, stream>>>(bedge, bbase, dis, rowptr, em, x, (__half*)B, N);

    // --- layer 1: pure 32-ch aggregate -> y0 (fp16, in C) ;
    //     h1' = silu(y0@W1+b1)*dis -> A ---
    k_agg32<<<AGG_BLOCKS, BT, 0, stream>>>((__half*)B, em, rowptr, dis, (__half*)C, N);
    k_mm32act<<<MM_BLOCKS, BT, 0, stream>>>((__half*)C, W1, b1, dis, A, N);

    // --- layer 2: z2 = y1 @ W2 -> B ; agg+bias+silu*dis -> A ---
    k_mm64<<<MM_BLOCKS, BT, 0, stream>>>(A, W2, B, N);
    k_agg64<true, __half><<<AGG_BLOCKS, BT, 0, stream>>>(B, em, rowptr, dis, b2, A, N);

    // --- layer 3: z3 = y2 @ W3 -> B ; agg+bias+silu (fp32) -> C ---
    k_mm64<<<MM_BLOCKS, BT, 0, stream>>>(A, W3, B, N);
    k_agg64<false, float><<<AGG_BLOCKS, BT, 0, stream>>>(B, em, rowptr, dis, b3, C, N);

    // --- mean pool ---
    hipMemsetAsync(acc, 0, (size_t)G * 64 * sizeof(float), stream);
    k_pool_partial<<<(N + 127) / 128, BT, 0, stream>>>(C, batch, acc, N);
    k_pool_final<<<(G * 64) / BT, BT, 0, stream>>>(acc, batch, out, N);
}

// Round 11
// 340.983 us; speedup vs baseline: 1.0170x; 1.0170x over previous
//
#include <hip/hip_runtime.h>
#include <hip/hip_fp16.h>
#include <math.h>

// GCN encoder, N=100000, E=1600000, C_IN=32, C_H=C_OUT=64, G=64.
// CSR build via two-level LDS counting sort (NO global atomics).
// em weight = ew*dis[dst]; dis[src] folded into features.
// R12: TRANSFORM-FIRST (agg(h)W == agg(hW)): tiny GEMMs + lean agg.
// R13: contiguous node chunks per wave + windowed edge-meta staging.
// R14: 4ch/lane uint2 gathers (NEUTRAL -> not issue-bound).
// R15: NB 256->1024. R16: spill-proof 2-threads/node GEMMs.
// R17 (REGRESSED): speculative 8-slot batches = duplicate gathers.
// R18: clean/tail split. 343us (best). agg64 44.6us @ occ 53%.
// R19 (NEUTRAL): node-pair interleave - deeper per-wave MLP but VGPR
// 28->44 and occ 53->37%: residency loss cancels pipelining gain.
// Lesson: per-wave pipelining trades against wave count here.
// R20: MORE WAVES, NOT DEEPER WAVES. Occupancy was grid-capped: 3125
// blocks = 12.2/CU vs the 8-block/CU HW residency cap -> time-avg 53%,
// VALU 42% idle. Nodes-per-wave 8->4 in both agg kernels: 6250 blocks
// = 24.4/CU -> sustained ~8 resident blocks/CU, ~2x latency-hiding
// TLP. agg64 inner loop reverted to the R18 optimum.

#define NB   1024       // dst buckets (128 nodes each; supports N < 131072)
#define BSH  7          // log2(nodes per bucket)
#define BMASK 127
#define BN   128        // nodes per bucket
#define PBLK 1024       // partition blocks
#define FIXP_SCALE 1048576.0f   // 2^20
#define FIXP_MASK  ((1ULL << 40) - 1)

__device__ __forceinline__ int lower_bound_i(const int* __restrict__ a, int n, int v) {
    int lo = 0, hi = n;
    while (lo < hi) {
        int m = (lo + hi) >> 1;
        if (a[m] < v) lo = m + 1; else hi = m;
    }
    return lo;
}

// A1: per-block histogram over NB dst-buckets (LDS atomics only)
__global__ __launch_bounds__(256) void k_bhist(const int* __restrict__ dst,
                                               int* __restrict__ hcnt, int e) {
    __shared__ int hist[NB];
    int tid = threadIdx.x, blk = blockIdx.x;
#pragma unroll
    for (int b = 0; b < NB / 256; ++b) hist[tid + 256 * b] = 0;
    __syncthreads();
    int chunk = (e + PBLK - 1) / PBLK;
    int lo = blk * chunk, hi = min(e, lo + chunk);
    for (int i = lo + tid; i < hi; i += 256)
        atomicAdd(&hist[dst[i] >> BSH], 1);
    __syncthreads();
#pragma unroll
    for (int b = 0; b < NB / 256; ++b) {
        int bb = tid + 256 * b;
        hcnt[bb * PBLK + blk] = hist[bb];   // [bucket][block] layout
    }
}

// A2a: per-bucket exclusive scan across the PBLK block-counts (in place) + totals
__global__ __launch_bounds__(256) void k_bscan(int* __restrict__ hcnt,
                                               int* __restrict__ btot) {
    __shared__ int s[256];
    int b = blockIdx.x, tid = threadIdx.x;
    int* row = hcnt + b * PBLK;
    int a0 = row[4 * tid], a1 = row[4 * tid + 1], a2 = row[4 * tid + 2], a3 = row[4 * tid + 3];
    int tsum = a0 + a1 + a2 + a3;
    s[tid] = tsum;
    __syncthreads();
    for (int off = 1; off < 256; off <<= 1) {
        int t = (tid >= off) ? s[tid - off] : 0;
        __syncthreads();
        s[tid] += t;
        __syncthreads();
    }
    int ex = s[tid] - tsum;
    row[4 * tid] = ex;
    row[4 * tid + 1] = ex + a0;
    row[4 * tid + 2] = ex + a0 + a1;
    row[4 * tid + 3] = ex + a0 + a1 + a2;
    if (tid == 255) btot[b] = s[255];
}

// A2b: scan NB bucket totals -> bucket_base[NB+1]; also rowptr[n]=e
__global__ __launch_bounds__(256) void k_bbase(const int* __restrict__ btot,
                                               int* __restrict__ bbase,
                                               int* __restrict__ rowptr, int n, int e) {
    __shared__ int s[256];
    int tid = threadIdx.x;
    int a0 = btot[4 * tid], a1 = btot[4 * tid + 1],
        a2 = btot[4 * tid + 2], a3 = btot[4 * tid + 3];
    int tsum = a0 + a1 + a2 + a3;
    s[tid] = tsum;
    __syncthreads();
    for (int off = 1; off < 256; off <<= 1) {
        int t = (tid >= off) ? s[tid - off] : 0;
        __syncthreads();
        s[tid] += t;
        __syncthreads();
    }
    int ex = s[tid] - tsum;
    bbase[4 * tid] = ex;
    bbase[4 * tid + 1] = ex + a0;
    bbase[4 * tid + 2] = ex + a0 + a1;
    bbase[4 * tid + 3] = ex + a0 + a1 + a2;
    if (tid == 255) bbase[NB] = s[255];   // == e
    if (tid == 0) rowptr[n] = e;
}

// A3: partition edges into buckets; pos from LDS cursor (no global atomics)
__global__ __launch_bounds__(256) void k_bpart(const int* __restrict__ src,
                                               const int* __restrict__ dst,
                                               const float* __restrict__ ew,
                                               const int* __restrict__ hcnt,
                                               const int* __restrict__ bbase,
                                               int2* __restrict__ bedge, int e) {
    __shared__ int cur[NB];
    int tid = threadIdx.x, blk = blockIdx.x;
#pragma unroll
    for (int b = 0; b < NB / 256; ++b) {
        int bb = tid + 256 * b;
        cur[bb] = bbase[bb] + hcnt[bb * PBLK + blk];
    }
    __syncthreads();
    int chunk = (e + PBLK - 1) / PBLK;
    int lo = blk * chunk, hi = min(e, lo + chunk);
    for (int i = lo + tid; i < hi; i += 256) {
        int d = dst[i];
        int pos = atomicAdd(&cur[d >> BSH], 1);          // LDS atomic
        bedge[pos] = make_int2(src[i] | ((d & BMASK) << 17), __float_as_int(ew[i]));
    }
}

// B: per-bucket (BN=128 nodes): LDS packed cnt + fixp sum(ew) -> dis,
// rowptr, then scatter (src, ew*dis[d]) grouped per node into em.
// Fused hs = fp16(dis*x) for this bucket's nodes. No global atomics.
__global__ __launch_bounds__(256) void k_bucket(const int2* __restrict__ bedge,
                                                const int* __restrict__ bbase,
                                                float* __restrict__ dis,
                                                int* __restrict__ rowptr,
                                                int2* __restrict__ em,
                                                const float* __restrict__ x,
                                                __half* __restrict__ hs, int n) {
    __shared__ unsigned long long pk[BN];
    __shared__ int cnt[BN];
    __shared__ int scn[BN];
    __shared__ float sdis[BN];
    __shared__ int cur[BN];
    int b = blockIdx.x, tid = threadIdx.x;
    int e0 = bbase[b], e1 = bbase[b + 1];
    if (tid < BN) pk[tid] = 0ULL;
    __syncthreads();
    for (int i = e0 + tid; i < e1; i += 256) {
        int2 v = bedge[i];
        int dlo = (v.x >> 17) & BMASK;
        unsigned long long p =
            (1ULL << 40) | (unsigned long long)(__int_as_float(v.y) * FIXP_SCALE);
        atomicAdd(&pk[dlo], p);                          // LDS atomic
    }
    __syncthreads();
    if (tid < BN) {
        unsigned long long v = pk[tid];
        int c = (int)(v >> 40);
        cnt[tid] = c; scn[tid] = c;
        sdis[tid] = rsqrtf(1.0f + (float)(v & FIXP_MASK) * (1.0f / FIXP_SCALE));
    }
    __syncthreads();
    // BN-entry inclusive scan (all threads hit the barriers)
    for (int off = 1; off < BN; off <<= 1) {
        int v0 = (tid >= off && tid < BN) ? scn[tid - off] : 0;
        __syncthreads();
        if (tid < BN) scn[tid] += v0;
        __syncthreads();
    }
    if (tid < BN) {
        int rb = e0 + scn[tid] - cnt[tid];               // exclusive
        cur[tid] = rb;
        int node = (b << BSH) + tid;
        if (node < n) { rowptr[node] = rb; dis[node] = sdis[tid]; }
    }
    __syncthreads();
    for (int i = e0 + tid; i < e1; i += 256) {
        int2 v = bedge[i];
        int dlo = (v.x >> 17) & BMASK;
        int pos = atomicAdd(&cur[dlo], 1);               // LDS atomic
        float w = __int_as_float(v.y) * sdis[dlo];
        em[pos] = make_int2(v.x & 0x1FFFF, __float_as_int(w));
    }
    // fused layer-1 pre-scale: hs = fp16(dis * x) for nodes of this bucket
    int nodebase = b << BSH;
    int nloc = n - nodebase; if (nloc > BN) nloc = BN;
    if (nloc > 0) {
        const float2* x2 = (const float2*)(x + (size_t)nodebase * 32);
        __half2* hs2 = (__half2*)(hs + (size_t)nodebase * 32);
        int total2 = nloc * 16;                    // 16 float2 per 32-ch row
        for (int i = tid; i < total2; i += 256) {
            float d = sdis[i >> 4];
            float2 v = x2[i];
            hs2[i] = __float22half2_rn(make_float2(v.x * d, v.y * d));
        }
    }
}

__device__ __forceinline__ float2 cvt_pair(unsigned int u) {
    __half2 h2 = *(__half2*)&u;
    return __half22float2(h2);
}

// R20: pure 32-ch aggregate, 4ch/lane, 16-edge units (2 slots) with
// clean/tail split; 4 NODES PER WAVE (2x waves for latency hiding).
// y0 = sum_e w_e hs[src] + di*hs[node].
__global__ __launch_bounds__(256, 4) void k_agg32(const __half* __restrict__ hs,
                                                  const int2* __restrict__ em,
                                                  const int* __restrict__ rowptr,
                                                  const float* __restrict__ dis,
                                                  __half* __restrict__ y0, int n) {
    __shared__ __align__(8) int2 sme[4][128];
    int lane = threadIdx.x & 63, wv = threadIdx.x >> 6;
    int c = lane & 7, oct = lane >> 3;
    const uint2* h64 = (const uint2*)hs;      // 8 uint2 per 32-ch row
    int wid = (blockIdx.x * blockDim.x + threadIdx.x) >> 6;
    int n0 = wid * 4;
    if (n0 >= n) return;
    int cnt = min(4, n - n0);
    int rp = 0;
    if (lane <= cnt) rp = rowptr[n0 + lane];
    int hiw = __shfl(rp, cnt, 64);            // end of wave's edge range
    int wlo = 0, whi = 0;                     // staged window [wlo, whi)
    for (int k = 0; k < cnt; ++k) {
        int node = n0 + k;
        int lo = __shfl(rp, k, 64), hi = __shfl(rp, k + 1, 64);
        float2 a0 = make_float2(0.0f, 0.0f), a1 = make_float2(0.0f, 0.0f);
        if (oct == 0) {
            float di = dis[node];
            uint2 sh = h64[(unsigned)(node * 8 + c)];
            float2 f0 = cvt_pair(sh.x), f1 = cvt_pair(sh.y);
            a0.x = di * f0.x; a0.y = di * f0.y;          // self: di^2*x = di*hs
            a1.x = di * f1.x; a1.y = di * f1.y;
        }
        int idx = lo;
        while (idx < hi) {
            if (idx >= whi) {                 // refill (wave-uniform)
                int i0 = idx + lane;
                if (i0 < hiw) sme[wv][lane] = em[i0];
                int i1 = i0 + 64;
                if (i1 < hiw) sme[wv][lane + 64] = em[i1];
                wlo = idx; whi = idx + 128;
            }
            int base = idx - wlo;
            int take = min(hi, whi) - idx;    // 1..128 edges this pass
            int g = 0;
            // clean 16-edge batches: no predication, no clamped dups
            for (; g + 16 <= take; g += 16) {
                int2 ev[2]; uint2 hv[2];
#pragma unroll
                for (int t = 0; t < 2; ++t)
                    ev[t] = sme[wv][base + g + 8 * t + oct];      // 8-way bcast
#pragma unroll
                for (int t = 0; t < 2; ++t)
                    hv[t] = h64[(unsigned)(ev[t].x * 8 + c)];
#pragma unroll
                for (int t = 0; t < 2; ++t) {
                    float ww = __int_as_float(ev[t].y);
                    float2 f0 = cvt_pair(hv[t].x), f1 = cvt_pair(hv[t].y);
                    a0.x = fmaf(ww, f0.x, a0.x);
                    a0.y = fmaf(ww, f0.y, a0.y);
                    a1.x = fmaf(ww, f1.x, a1.x);
                    a1.y = fmaf(ww, f1.y, a1.y);
                }
            }
            if (g < take) {                   // predicated tail (<=15 edges)
                int2 ev[2]; uint2 hv[2]; int pr[2];
#pragma unroll
                for (int t = 0; t < 2; ++t) {
                    int p = g + 8 * t + oct;
                    pr[t] = p < take;
                    int pc = pr[t] ? p : 0;               // clamp: stay in window
                    ev[t] = sme[wv][base + pc];
                }
#pragma unroll
                for (int t = 0; t < 2; ++t)
                    hv[t] = h64[(unsigned)(ev[t].x * 8 + c)];
#pragma unroll
                for (int t = 0; t < 2; ++t) {
                    float ww = pr[t] ? __int_as_float(ev[t].y) : 0.0f;
                    float2 f0 = cvt_pair(hv[t].x), f1 = cvt_pair(hv[t].y);
                    a0.x = fmaf(ww, f0.x, a0.x);
                    a0.y = fmaf(ww, f0.y, a0.y);
                    a1.x = fmaf(ww, f1.x, a1.x);
                    a1.y = fmaf(ww, f1.y, a1.y);
                }
            }
            idx += take;
        }
        // reduce across octs
        a0.x += __shfl_down(a0.x, 32, 64); a0.y += __shfl_down(a0.y, 32, 64);
        a1.x += __shfl_down(a1.x, 32, 64); a1.y += __shfl_down(a1.y, 32, 64);
        a0.x += __shfl_down(a0.x, 16, 64); a0.y += __shfl_down(a0.y, 16, 64);
        a1.x += __shfl_down(a1.x, 16, 64); a1.y += __shfl_down(a1.y, 16, 64);
        a0.x += __shfl_down(a0.x, 8, 64);  a0.y += __shfl_down(a0.y, 8, 64);
        a1.x += __shfl_down(a1.x, 8, 64);  a1.y += __shfl_down(a1.y, 8, 64);
        if (oct == 0) {
            uint2 o;
            __half2 p0 = __float22half2_rn(make_float2(a0.x, a0.y));
            __half2 p1 = __float22half2_rn(make_float2(a1.x, a1.y));
            o.x = *(unsigned int*)&p0; o.y = *(unsigned int*)&p1;
            ((uint2*)y0)[(size_t)node * 8 + c] = o;
        }
    }
}

// R16: h1' = silu(y0 @ W1 + b1) * dis.  2 THREADS PER NODE.
__global__ __launch_bounds__(256, 4) void k_mm32act(const __half* __restrict__ y0,
                                                    const float* __restrict__ W,
                                                    const float* __restrict__ bias,
                                                    const float* __restrict__ dis,
                                                    __half* __restrict__ out, int n) {
    __shared__ __align__(16) float sw[32 * 64 + 64];
#pragma unroll
    for (int i = 0; i < 8; ++i)
        sw[threadIdx.x + 256 * i] = W[threadIdx.x + 256 * i];
    if (threadIdx.x < 64) sw[2048 + threadIdx.x] = bias[threadIdx.x];
    __syncthreads();
    int idx = blockIdx.x * 256 + threadIdx.x;
    int node = idx >> 1, half = idx & 1;
    if (node >= n) return;
    const uint4* yrow = (const uint4*)(y0 + (size_t)node * 32);
    float o[32];
#pragma unroll
    for (int j = 0; j < 32; ++j) o[j] = sw[2048 + half * 32 + j];
#pragma unroll
    for (int kb = 0; kb < 2; ++kb) {           // 2 chunks of 16 channels
        uint4 ya = yrow[2 * kb], yb = yrow[2 * kb + 1];
        unsigned int yw[8] = {ya.x, ya.y, ya.z, ya.w, yb.x, yb.y, yb.z, yb.w};
#pragma unroll
        for (int k2 = 0; k2 < 8; ++k2) {
            float2 yk = cvt_pair(yw[k2]);
            int k = kb * 16 + 2 * k2;
            const float4* r0 = (const float4*)&sw[k * 64 + half * 32];
            const float4* r1 = (const float4*)&sw[(k + 1) * 64 + half * 32];
#pragma unroll
            for (int j4 = 0; j4 < 8; ++j4) {
                float4 w0 = r0[j4];
                float4 w1 = r1[j4];
                o[4 * j4 + 0] = fmaf(yk.y, w1.x, fmaf(yk.x, w0.x, o[4 * j4 + 0]));
                o[4 * j4 + 1] = fmaf(yk.y, w1.y, fmaf(yk.x, w0.y, o[4 * j4 + 1]));
                o[4 * j4 + 2] = fmaf(yk.y, w1.z, fmaf(yk.x, w0.z, o[4 * j4 + 2]));
                o[4 * j4 + 3] = fmaf(yk.y, w1.w, fmaf(yk.x, w0.w, o[4 * j4 + 3]));
            }
        }
    }
    float dsc = dis[node];
    __half2* orow = (__half2*)(out + (size_t)node * 64 + half * 32);
#pragma unroll
    for (int j2 = 0; j2 < 16; ++j2) {
        float ox = o[2 * j2], oy = o[2 * j2 + 1];
        ox = ox / (1.0f + __expf(-ox)) * dsc;
        oy = oy / (1.0f + __expf(-oy)) * dsc;
        orow[j2] = __float22half2_rn(make_float2(ox, oy));
    }
}

// R16: z = y @ W  (N x 64 fp16 in, 64x64 fp32 W in LDS, N x 64 fp16 out).
// 2 THREADS PER NODE (half = 32 outputs each); spill-proof.
__global__ __launch_bounds__(256, 4) void k_mm64(const __half* __restrict__ y,
                                                 const float* __restrict__ W,
                                                 __half* __restrict__ z, int n) {
    __shared__ __align__(16) float sw[64 * 64];     // 16 KB
#pragma unroll
    for (int i = 0; i < 16; ++i)
        sw[threadIdx.x + 256 * i] = W[threadIdx.x + 256 * i];
    __syncthreads();
    int idx = blockIdx.x * 256 + threadIdx.x;
    int node = idx >> 1, half = idx & 1;
    if (node >= n) return;
    const uint4* yrow = (const uint4*)(y + (size_t)node * 64);
    float o[32];
#pragma unroll
    for (int j = 0; j < 32; ++j) o[j] = 0.0f;
#pragma unroll
    for (int kb = 0; kb < 4; ++kb) {           // 4 chunks of 16 channels
        uint4 ya = yrow[2 * kb], yb = yrow[2 * kb + 1];
        unsigned int yw[8] = {ya.x, ya.y, ya.z, ya.w, yb.x, yb.y, yb.z, yb.w};
#pragma unroll
        for (int k2 = 0; k2 < 8; ++k2) {
            float2 yk = cvt_pair(yw[k2]);
            int k = kb * 16 + 2 * k2;
            const float4* r0 = (const float4*)&sw[k * 64 + half * 32];
            const float4* r1 = (const float4*)&sw[(k + 1) * 64 + half * 32];
#pragma unroll
            for (int j4 = 0; j4 < 8; ++j4) {
                float4 w0 = r0[j4];
                float4 w1 = r1[j4];
                o[4 * j4 + 0] = fmaf(yk.y, w1.x, fmaf(yk.x, w0.x, o[4 * j4 + 0]));
                o[4 * j4 + 1] = fmaf(yk.y, w1.y, fmaf(yk.x, w0.y, o[4 * j4 + 1]));
                o[4 * j4 + 2] = fmaf(yk.y, w1.z, fmaf(yk.x, w0.z, o[4 * j4 + 2]));
                o[4 * j4 + 3] = fmaf(yk.y, w1.w, fmaf(yk.x, w0.w, o[4 * j4 + 3]));
            }
        }
    }
    __half2* zrow = (__half2*)(z + (size_t)node * 64 + half * 32);
#pragma unroll
    for (int j2 = 0; j2 < 16; ++j2)
        zrow[j2] = __float22half2_rn(make_float2(o[2 * j2], o[2 * j2 + 1]));
}

// R20: lean 64-ch aggregate, 4ch/lane, 16-edge units (4 slots) with
// clean/tail split (R18 optimum inner loop); 4 NODES PER WAVE.
// out = [di*] silu( sum_e w_e z[src] + di*z[node] + bias ).
template <bool SCALE, typename OUT>
__global__ __launch_bounds__(256, 4) void k_agg64(const __half* __restrict__ z,
                                                  const int2* __restrict__ em,
                                                  const int* __restrict__ rowptr,
                                                  const float* __restrict__ dis,
                                                  const float* __restrict__ bias,
                                                  OUT* __restrict__ out, int n) {
    __shared__ __align__(8) int2 sme[4][128];
    int lane = threadIdx.x & 63, wv = threadIdx.x >> 6;
    int c = lane & 15, quarter = lane >> 4;
    const uint2* h64 = (const uint2*)z;       // 16 uint2 per 64-ch row
    float4 bv4 = ((const float4*)bias)[c];
    int wid = (blockIdx.x * blockDim.x + threadIdx.x) >> 6;
    int n0 = wid * 4;
    if (n0 >= n) return;
    int cnt = min(4, n - n0);
    int rp = 0;
    if (lane <= cnt) rp = rowptr[n0 + lane];
    int hiw = __shfl(rp, cnt, 64);
    int wlo = 0, whi = 0;
    for (int k = 0; k < cnt; ++k) {
        int node = n0 + k;
        int lo = __shfl(rp, k, 64), hi = __shfl(rp, k + 1, 64);
        float di = 0.0f;
        float2 a0 = make_float2(0.0f, 0.0f), a1 = make_float2(0.0f, 0.0f);
        if (quarter == 0) {
            di = dis[node];
            uint2 sh = h64[(unsigned)(node * 16 + c)];
            float2 f0 = cvt_pair(sh.x), f1 = cvt_pair(sh.y);
            a0.x = di * f0.x; a0.y = di * f0.y;          // self-loop term
            a1.x = di * f1.x; a1.y = di * f1.y;
        }
        int idx = lo;
        while (idx < hi) {
            if (idx >= whi) {                 // refill (wave-uniform)
                int i0 = idx + lane;
                if (i0 < hiw) sme[wv][lane] = em[i0];
                int i1 = i0 + 64;
                if (i1 < hiw) sme[wv][lane + 64] = em[i1];
                wlo = idx; whi = idx + 128;
            }
            int base = idx - wlo;
            int take = min(hi, whi) - idx;
            int g = 0;
            // clean 16-edge batches: no predication, no clamped dups
            for (; g + 16 <= take; g += 16) {
                int2 ev[4]; uint2 hv[4];
#pragma unroll
                for (int t = 0; t < 4; ++t)
                    ev[t] = sme[wv][base + g + 4 * t + quarter];  // 4-way bcast
#pragma unroll
                for (int t = 0; t < 4; ++t)
                    hv[t] = h64[(unsigned)(ev[t].x * 16 + c)];
#pragma unroll
                for (int t = 0; t < 4; ++t) {
                    float ww = __int_as_float(ev[t].y);
                    float2 f0 = cvt_pair(hv[t].x), f1 = cvt_pair(hv[t].y);
                    a0.x = fmaf(ww, f0.x, a0.x);
                    a0.y = fmaf(ww, f0.y, a0.y);
                    a1.x = fmaf(ww, f1.x, a1.x);
                    a1.y = fmaf(ww, f1.y, a1.y);
                }
            }
            if (g < take) {                   // predicated tail (<=15 edges)
                int2 ev[4]; uint2 hv[4]; int pr[4];
#pragma unroll
                for (int t = 0; t < 4; ++t) {
                    int p = g + 4 * t + quarter;
                    pr[t] = p < take;
                    int pc = pr[t] ? p : 0;               // clamp: stay in window
                    ev[t] = sme[wv][base + pc];
                }
#pragma unroll
                for (int t = 0; t < 4; ++t)
                    hv[t] = h64[(unsigned)(ev[t].x * 16 + c)];
#pragma unroll
                for (int t = 0; t < 4; ++t) {
                    float ww = pr[t] ? __int_as_float(ev[t].y) : 0.0f;
                    float2 f0 = cvt_pair(hv[t].x), f1 = cvt_pair(hv[t].y);
                    a0.x = fmaf(ww, f0.x, a0.x);
                    a0.y = fmaf(ww, f0.y, a0.y);
                    a1.x = fmaf(ww, f1.x, a1.x);
                    a1.y = fmaf(ww, f1.y, a1.y);
                }
            }
            idx += take;
        }
        a0.x += __shfl_down(a0.x, 32, 64); a0.y += __shfl_down(a0.y, 32, 64);
        a1.x += __shfl_down(a1.x, 32, 64); a1.y += __shfl_down(a1.y, 32, 64);
        a0.x += __shfl_down(a0.x, 16, 64); a0.y += __shfl_down(a0.y, 16, 64);
        a1.x += __shfl_down(a1.x, 16, 64); a1.y += __shfl_down(a1.y, 16, 64);
        if (quarter == 0) {
            float ox = a0.x + bv4.x, oy = a0.y + bv4.y;
            float oz = a1.x + bv4.z, ow = a1.y + bv4.w;
            ox = ox / (1.0f + __expf(-ox));
            oy = oy / (1.0f + __expf(-oy));
            oz = oz / (1.0f + __expf(-oz));
            ow = ow / (1.0f + __expf(-ow));
            if (SCALE) { ox *= di; oy *= di; oz *= di; ow *= di; }
            if (sizeof(OUT) == 2) {
                uint2 o;
                __half2 p0 = __float22half2_rn(make_float2(ox, oy));
                __half2 p1 = __float22half2_rn(make_float2(oz, ow));
                o.x = *(unsigned int*)&p0; o.y = *(unsigned int*)&p1;
                ((uint2*)out)[(size_t)node * 16 + c] = o;
            } else {
                ((float4*)out)[(size_t)node * 16 + c] = make_float4(ox, oy, oz, ow);
            }
        }
    }
}

// pool phase 1: 128-row chunks, segment-flush atomics into acc[G*64]
__global__ void k_pool_partial(const float* __restrict__ h, const int* __restrict__ batch,
                               float* __restrict__ acc, int n) {
    int c = threadIdx.x & 63, r = threadIdx.x >> 6;
    int base = blockIdx.x * 128;
    int end = base + 128; if (end > n) end = n;
    float part = 0.0f;
    int cur = -1;
    for (int i = base + r; i < end; i += 4) {
        int g = batch[i];
        if (g != cur) {
            if (cur >= 0) atomicAdd(&acc[cur * 64 + c], part);
            part = 0.0f;
            cur = g;
        }
        part += h[(size_t)i * 64 + c];
    }
    if (cur >= 0) atomicAdd(&acc[cur * 64 + c], part);
}

// pool phase 2: divide by per-graph count
__global__ void k_pool_final(const float* __restrict__ acc, const int* __restrict__ batch,
                             float* __restrict__ out, int n) {
    int idx = blockIdx.x * blockDim.x + threadIdx.x;   // G*64 threads
    int g = idx >> 6;
    int lo = lower_bound_i(batch, n, g);
    int hi = lower_bound_i(batch, n, g + 1);
    int cnt = hi - lo;
    out[idx] = acc[idx] / (float)(cnt > 0 ? cnt : 1);
}

extern "C" void kernel_launch(void* const* d_in, const int* in_sizes, int n_in,
                              void* d_out, int out_size, void* d_ws, size_t ws_size,
                              hipStream_t stream) {
    const float* x   = (const float*)d_in[0];
    const float* ew  = (const float*)d_in[1];
    const float* W1  = (const float*)d_in[2];
    const float* b1  = (const float*)d_in[3];
    const float* W2  = (const float*)d_in[4];
    const float* b2  = (const float*)d_in[5];
    const float* W3  = (const float*)d_in[6];
    const float* b3  = (const float*)d_in[7];
    const int*   eidx  = (const int*)d_in[8];
    const int*   batch = (const int*)d_in[9];
    float* out = (float*)d_out;

    const int E = in_sizes[1];       // 1,600,000
    const int N = in_sizes[9];       // 100,000 (< 131072: fits 17-bit src pack)
    const int G = 64;
    const int* src = eidx;
    const int* dst = eidx + E;

    // workspace: A/B (fp16 features) double as CSR-build scratch
    // (bedge in A: E*8B == N*64*2B exactly; hcnt/btot in B: 4MB+4KB);
    // C holds the fp16 y0 aggregate early, then the final fp32 layer.
    char* p = (char*)d_ws;
    __half* A     = (__half*)p;                p += (size_t)N * 64 * sizeof(__half);
    __half* B     = (__half*)p;                p += (size_t)N * 64 * sizeof(__half);
    float* C      = (float*)p;                 p += (size_t)N * 64 * sizeof(float);
    float* dis    = (float*)p;                 p += (size_t)N * sizeof(float);
    int*   rowptr = (int*)p;                   p += (size_t)(N + 1) * sizeof(int);
    int*   bbase  = (int*)p;                   p += (size_t)(NB + 1) * sizeof(int);
    float* acc    = (float*)p;                 p += (size_t)G * 64 * sizeof(float);
    p = (char*)(((uintptr_t)p + 7) & ~(uintptr_t)7);
    int2*  em     = (int2*)p;                  // E entries, 8B

    int2* bedge = (int2*)A;                    // E*8B == N*64*2B
    int*  hcnt  = (int*)B;                     // NB*PBLK*4B = 4MB
    int*  btot  = (int*)B + NB * PBLK;         // NB ints

    const int BT = 256;
    const int WAVES = (N + 3) / 4;             // 25000 waves, 4 contiguous nodes each
    const int AGG_BLOCKS = (WAVES + 3) / 4;    // 6250 -> 24.4 blocks/CU
    const int MM_BLOCKS = (2 * N + 255) / 256; // 782, 2 threads per node

    // --- CSR build: LDS counting sort, zero global atomics ---
    k_bhist<<<PBLK, 256, 0, stream>>>(dst, hcnt, E);
    k_bscan<<<NB, 256, 0, stream>>>(hcnt, btot);
    k_bbase<<<1, 256, 0, stream>>>(btot, bbase, rowptr, N, E);
    k_bpart<<<PBLK, 256, 0, stream>>>(src, dst, ew, hcnt, bbase, bedge, E);
    // k_bucket also emits hs = fp16(dis*x) into B (hcnt scratch dead here)
    k_bucket<<<NB, 256, 0, stream>>>(bedge, bbase, dis, rowptr, em, x, (__half*)B, N);

    // --- layer 1: pure 32-ch aggregate -> y0 (fp16, in C) ;
    //     h1' = silu(y0@W1+b1)*dis -> A ---
    k_agg32<<<AGG_BLOCKS, BT, 0, stream>>>((__half*)B, em, rowptr, dis, (__half*)C, N);
    k_mm32act<<<MM_BLOCKS, BT, 0, stream>>>((__half*)C, W1, b1, dis, A, N);

    // --- layer 2: z2 = y1 @ W2 -> B ; agg+bias+silu*dis -> A ---
    k_mm64<<<MM_BLOCKS, BT, 0, stream>>>(A, W2, B, N);
    k_agg64<true, __half><<<AGG_BLOCKS, BT, 0, stream>>>(B, em, rowptr, dis, b2, A, N);

    // --- layer 3: z3 = y2 @ W3 -> B ; agg+bias+silu (fp32) -> C ---
    k_mm64<<<MM_BLOCKS, BT, 0, stream>>>(A, W3, B, N);
    k_agg64<false, float><<<AGG_BLOCKS, BT, 0, stream>>>(B, em, rowptr, dis, b3, C, N);

    // --- mean pool ---
    hipMemsetAsync(acc, 0, (size_t)G * 64 * sizeof(float), stream);
    k_pool_partial<<<(N + 127) / 128, BT, 0, stream>>>(C, batch, acc, N);
    k_pool_final<<<(G * 64) / BT, BT, 0, stream>>>(acc, batch, out, N);
}